// Round 12
// baseline (54.337 us; speedup 1.0000x reference)
//
#include <hip/hip_runtime.h>

// (B,N,F) = (8, 4096, 256), fp32 in/out. out = (B, 5, F).
constexpr int B = 8;
constexpr int N = 4096;
constexpr int F = 256;
constexpr int F4 = F / 4;          // 64 float4 per row
constexpr int CH1 = 128;           // K1/K3 chunks per batch (4 blocks/CU)
constexpr int R1  = N / CH1;       // 32 rows per block
constexpr int W1  = R1 / 4;        // 8 rows per wave
constexpr int CH2 = 64;            // K2 chunks per batch
constexpr int R2  = N / CH2;       // 64 rows per block
constexpr int W2  = R2 / 4;        // 16 rows per wave

// Monotone float->uint mapping: f<g  <=>  sortable(f)<sortable(g)
__device__ __forceinline__ unsigned sortable_f32(float f) {
    unsigned u = __float_as_uint(f);
    return (u & 0x80000000u) ? ~u : (u | 0x80000000u);
}

__device__ __forceinline__ unsigned long long agent_load_u64(const unsigned long long* p) {
    return __hip_atomic_load(p, __ATOMIC_RELAXED, __HIP_MEMORY_SCOPE_AGENT);
}

// ---------------- K1: co-stream ref_flow AND sup_flow column partials ----------------
// Both 32MB streams issue concurrently (overlapped HBM; warms sup_flow into L3 for K3).
__global__ void k1_colsum(const float* __restrict__ ref_flow, const float* __restrict__ sup_flow,
                          float* __restrict__ partial, float* __restrict__ partialS,
                          int* __restrict__ cnt, unsigned long long* __restrict__ minbase,
                          unsigned long long* __restrict__ maxbase) {
    const int b = blockIdx.x, chunk = blockIdx.y;
    const int t = threadIdx.x, wave = t >> 6, lane = t & 63;
    const int w8 = wave * W1;
    __shared__ float4 red[4][F4];
    __shared__ float4 redS[4][F4];

    const float4* rbase = reinterpret_cast<const float4*>(ref_flow)
                        + ((size_t)b * N + (size_t)chunk * R1) * F4;
    const float4* sbase = reinterpret_cast<const float4*>(sup_flow)
                        + ((size_t)b * N + (size_t)chunk * R1) * F4;

    float4 acc  = make_float4(0.f, 0.f, 0.f, 0.f);
    float4 accS = make_float4(0.f, 0.f, 0.f, 0.f);
    // interleave the two streams: 16 independent loads in the instruction window
    #pragma unroll
    for (int i = 0; i < W1; ++i) {
        float4 v = rbase[(size_t)(w8 + i) * F4 + lane];
        float4 s = sbase[(size_t)(w8 + i) * F4 + lane];
        acc.x  += v.x; acc.y  += v.y; acc.z  += v.z; acc.w  += v.w;
        accS.x += s.x; accS.y += s.y; accS.z += s.z; accS.w += s.w;
    }
    red[wave][lane]  = acc;
    redS[wave][lane] = accS;
    __syncthreads();
    if (wave == 0) {
        float4 a0 = red[0][lane], a1 = red[1][lane], a2 = red[2][lane], a3 = red[3][lane];
        float4 s = make_float4(a0.x + a1.x + a2.x + a3.x, a0.y + a1.y + a2.y + a3.y,
                               a0.z + a1.z + a2.z + a3.z, a0.w + a1.w + a2.w + a3.w);
        reinterpret_cast<float4*>(partial)[((size_t)b * CH1 + chunk) * F4 + lane] = s;
    } else if (wave == 1) {
        float4 a0 = redS[0][lane], a1 = redS[1][lane], a2 = redS[2][lane], a3 = redS[3][lane];
        float4 s = make_float4(a0.x + a1.x + a2.x + a3.x, a0.y + a1.y + a2.y + a3.y,
                               a0.z + a1.z + a2.z + a3.z, a0.w + a1.w + a2.w + a3.w);
        // keeps the sup loads live; nothing reads this (sup colsum has no consumer)
        reinterpret_cast<float4*>(partialS)[((size_t)b * CH1 + chunk) * F4 + lane] = s;
    }
    // zero-init per-batch slots + both last-arriver counters (boundary-flushed)
    if (chunk == 0) {
        if (t < 3) minbase[(size_t)b * 16 + t] = 0ull;
        if (t < 2) maxbase[(size_t)b * 16 + t] = 0ull;
        if (t == 0) { cnt[b * 32] = 0; cnt[(B + b) * 32] = 0; }
    }
}

// ---------------- K2: redundant S-reduce (L2-broadcast) + dot1 (L3-hot) + top3 -> slots;
//                      last-arriver: decode, Tv -> ws, out rows 0-2 ----------------
__global__ void k2_dot1(const float* __restrict__ ref_rgb, const float* __restrict__ ref_flow,
                        const float* __restrict__ partial, float* __restrict__ Tvg,
                        float* __restrict__ out,
                        unsigned long long* __restrict__ minbase, int* __restrict__ cnt) {
    const int b = blockIdx.x, chunk = blockIdx.y;
    const int t = threadIdx.x, wave = t >> 6, lane = t & 63;
    const int w16 = wave * W2;
    __shared__ float S[F];
    __shared__ float scoreS[R2];
    __shared__ int   chosen[3];
    __shared__ int   lastFlag;

    unsigned long long* minslot = minbase + (size_t)b * 16;

    // redundant S-reduce: 128KB per batch, same data for 64 blocks -> L2 broadcast
    {
        float sacc = 0.f;
        const float* pb = partial + (size_t)b * CH1 * F + t;
        #pragma unroll 8
        for (int p = 0; p < CH1; ++p) sacc += pb[(size_t)p * F];
        S[t] = sacc;
    }
    __syncthreads();

    // dot1: stream my ref rows (L3-hot after K1), load-FMA immediate
    const float4* rbase = reinterpret_cast<const float4*>(ref_flow)
                        + ((size_t)b * N + (size_t)chunk * R2) * F4;
    {
        float4 s4 = reinterpret_cast<const float4*>(S)[lane];
        #pragma unroll
        for (int i = 0; i < W2; ++i) {
            float4 a = rbase[(size_t)(w16 + i) * F4 + lane];
            float d = a.x * s4.x + a.y * s4.y + a.z * s4.z + a.w * s4.w;
            #pragma unroll
            for (int off = 32; off; off >>= 1) d += __shfl_xor(d, off);
            if (lane == 0) scoreS[w16 + i] = d;
        }
    }
    __syncthreads();

    // wave0: top-3 min -> lock-free bubbling slot insert (exact top-3, order-free)
    if (wave == 0) {
        const unsigned gidx = (unsigned)(chunk * R2 + lane);   // R2 == 64 == lanes
        unsigned long long inv =
            ~((((unsigned long long)sortable_f32(scoreS[lane])) << 32) | (unsigned long long)gidx);
        unsigned long long cur = inv;
        for (int k = 0; k < 3; ++k) {
            unsigned long long m = cur;
            #pragma unroll
            for (int off = 32; off; off >>= 1) {
                unsigned long long o = __shfl_xor(m, off);
                if (o > m) m = o;
            }
            if (lane == 0) {
                unsigned long long x = m;
                #pragma unroll
                for (int s = 0; s < 3; ++s) {
                    unsigned long long old = atomicMax(&minslot[s], x);
                    x = (old < x) ? old : x;
                }
            }
            if (cur == m) cur = 0;
        }
    }

    // last arriver per batch (no spin): decode top-3, Tv -> ws, out rows 0-2
    asm volatile("s_waitcnt vmcnt(0)" ::: "memory");   // my slot atomics globally visible
    __syncthreads();
    if (t == 0) {
        int old = __hip_atomic_fetch_add(cnt + b * 32, 1,
                                         __ATOMIC_RELAXED, __HIP_MEMORY_SCOPE_AGENT);
        lastFlag = (old == CH2 - 1);
    }
    __syncthreads();
    if (lastFlag) {
        if (t == 0) {
            unsigned long long y0 = agent_load_u64(&minslot[0]);
            unsigned long long y1 = agent_load_u64(&minslot[1]);
            unsigned long long y2 = agent_load_u64(&minslot[2]);
            unsigned long long tmp;
            if (y1 > y0) { tmp = y0; y0 = y1; y1 = tmp; }
            if (y2 > y0) { tmp = y0; y0 = y2; y2 = tmp; }
            if (y2 > y1) { tmp = y1; y1 = y2; y2 = tmp; }
            chosen[0] = (int)((~y0) & 0xFFFFFFFFull);
            chosen[1] = (int)((~y1) & 0xFFFFFFFFull);
            chosen[2] = (int)((~y2) & 0xFFFFFFFFull);
        }
        __syncthreads();
        const int i0 = chosen[0], i1 = chosen[1], i2 = chosen[2];
        Tvg[(size_t)b * F + t] = ref_flow[((size_t)b * N + i0) * F + t]
                               + ref_flow[((size_t)b * N + i1) * F + t]
                               + ref_flow[((size_t)b * N + i2) * F + t];
        out[((size_t)b * 5 + 0) * F + t] = ref_rgb[((size_t)b * N + i0) * F + t];
        out[((size_t)b * 5 + 1) * F + t] = ref_rgb[((size_t)b * N + i1) * F + t];
        out[((size_t)b * 5 + 2) * F + t] = ref_rgb[((size_t)b * N + i2) * F + t];
    }
}

// ---------------- K3: Tv (one 16B load) -> immediate sup stream (L3-warm) + top2 -> slots;
//                      last-arriver: decode + gather rows 3-4 ----------------
__global__ void k3_dot2(const float* __restrict__ sup_rgb, const float* __restrict__ sup_flow,
                        const float* __restrict__ Tvg, float* __restrict__ out,
                        unsigned long long* __restrict__ maxbase, int* __restrict__ cnt) {
    const int b = blockIdx.x, chunk = blockIdx.y;
    const int t = threadIdx.x, wave = t >> 6, lane = t & 63;
    const int w8 = wave * W1;
    __shared__ float scoreS[R1];
    __shared__ int   chosen[2];
    __shared__ int   lastFlag;

    unsigned long long* maxslot = maxbase + (size_t)b * 16;

    float4 tv4 = reinterpret_cast<const float4*>(Tvg)[(size_t)b * F4 + lane];
    const float4* sbase = reinterpret_cast<const float4*>(sup_flow)
                        + ((size_t)b * N + (size_t)chunk * R1) * F4;
    #pragma unroll
    for (int i = 0; i < W1; ++i) {
        float4 a = sbase[(size_t)(w8 + i) * F4 + lane];
        float d = a.x * tv4.x + a.y * tv4.y + a.z * tv4.z + a.w * tv4.w;
        #pragma unroll
        for (int off = 32; off; off >>= 1) d += __shfl_xor(d, off);
        if (lane == 0) scoreS[w8 + i] = d;
    }
    __syncthreads();

    if (wave == 0) {
        // packed: larger == larger score, tie -> smaller index. lanes >= R1: sentinel 0.
        const unsigned gidx = (unsigned)(chunk * R1 + lane);
        unsigned long long pk = 0;
        if (lane < R1)
            pk = (((unsigned long long)sortable_f32(scoreS[lane])) << 32) |
                 (unsigned long long)(0xFFFFFFFFu - gidx);
        unsigned long long cur = pk;
        for (int k = 0; k < 2; ++k) {
            unsigned long long m = cur;
            #pragma unroll
            for (int off = 32; off; off >>= 1) {
                unsigned long long o = __shfl_xor(m, off);
                if (o > m) m = o;
            }
            if (lane == 0) {
                unsigned long long x = m;
                #pragma unroll
                for (int s = 0; s < 2; ++s) {
                    unsigned long long old = atomicMax(&maxslot[s], x);
                    x = (old < x) ? old : x;
                }
            }
            if (cur == m) cur = 0;
        }
    }

    // last arriver per batch (no spin) decodes top-2 and gathers rows 3-4
    asm volatile("s_waitcnt vmcnt(0)" ::: "memory");
    __syncthreads();
    if (t == 0) {
        int old = __hip_atomic_fetch_add(cnt + (B + b) * 32, 1,
                                         __ATOMIC_RELAXED, __HIP_MEMORY_SCOPE_AGENT);
        lastFlag = (old == CH1 - 1);
    }
    __syncthreads();
    if (lastFlag) {
        if (t == 0) {
            unsigned long long y0 = agent_load_u64(&maxslot[0]);
            unsigned long long y1 = agent_load_u64(&maxslot[1]);
            if (y1 > y0) { unsigned long long tmp = y0; y0 = y1; y1 = tmp; }
            chosen[0] = (int)(0xFFFFFFFFu - (unsigned)(y0 & 0xFFFFFFFFull));
            chosen[1] = (int)(0xFFFFFFFFu - (unsigned)(y1 & 0xFFFFFFFFull));
        }
        __syncthreads();
        out[((size_t)b * 5 + 3) * F + t] = sup_rgb[((size_t)b * N + chosen[0]) * F + t];
        out[((size_t)b * 5 + 4) * F + t] = sup_rgb[((size_t)b * N + chosen[1]) * F + t];
    }
}

extern "C" void kernel_launch(void* const* d_in, const int* in_sizes, int n_in,
                              void* d_out, int out_size, void* d_ws, size_t ws_size,
                              hipStream_t stream) {
    const float* ref_rgb  = (const float*)d_in[0];
    const float* ref_flow = (const float*)d_in[1];
    const float* sup_rgb  = (const float*)d_in[2];
    const float* sup_flow = (const float*)d_in[3];
    float* out = (float*)d_out;

    // ws: [0,2048) counters (2 sets x 8 batches x 128B) | [4096,5120) minslots |
    //     [8192,9216) maxslots | [12288,20480) Tv (8 x 256 f32) |
    //     [32768, +1MB) partial | [+1MB, +2MB) partialS (sup warm sink)
    int* cnt = (int*)d_ws;
    unsigned long long* minbase = (unsigned long long*)((char*)d_ws + 4096);
    unsigned long long* maxbase = (unsigned long long*)((char*)d_ws + 8192);
    float* Tvg      = (float*)((char*)d_ws + 12288);
    float* partial  = (float*)((char*)d_ws + 32768);
    float* partialS = partial + (size_t)B * CH1 * F;

    k1_colsum<<<dim3(B, CH1), 256, 0, stream>>>(ref_flow, sup_flow, partial, partialS,
                                                cnt, minbase, maxbase);
    k2_dot1<<<dim3(B, CH2), 256, 0, stream>>>(ref_rgb, ref_flow, partial, Tvg, out, minbase, cnt);
    k3_dot2<<<dim3(B, CH1), 256, 0, stream>>>(sup_rgb, sup_flow, Tvg, out, maxbase, cnt);
}

// Round 13
// 51.331 us; speedup vs baseline: 1.0586x; 1.0586x over previous
//
#include <hip/hip_runtime.h>

// (B,N,F) = (8, 4096, 256), fp32 in/out. out = (B, 5, F).
constexpr int B = 8;
constexpr int N = 4096;
constexpr int F = 256;
constexpr int F4 = F / 4;        // 64 float4 per row
constexpr int CH = 128;          // chunks (blocks) per batch, all kernels
constexpr int R = N / CH;        // 32 rows per block
constexpr int RPW = R / 4;       // 8 rows per wave

// Monotone float->uint mapping: f<g  <=>  sortable(f)<sortable(g)
__device__ __forceinline__ unsigned sortable_f32(float f) {
    unsigned u = __float_as_uint(f);
    return (u & 0x80000000u) ? ~u : (u | 0x80000000u);
}

__device__ __forceinline__ unsigned long long agent_load_u64(const unsigned long long* p) {
    return __hip_atomic_load(p, __ATOMIC_RELAXED, __HIP_MEMORY_SCOPE_AGENT);
}

// Direct global->LDS copy, 16B per lane, zero VGPR destination cost.
// LDS dest = wave-uniform base + lane*16 (HW rule); global src is per-lane.
__device__ __forceinline__ void gload_lds16(const float4* gsrc, float4* ldst) {
    __builtin_amdgcn_global_load_lds(
        (const __attribute__((address_space(1))) void*)gsrc,
        (__attribute__((address_space(3))) void*)ldst,
        16, 0, 0);
}

// ---------------- K1: stage ref rows -> LDS (full-rate stream), colsum from LDS ----------------
__global__ void k1_colsum(const float* __restrict__ ref_flow, float* __restrict__ partial,
                          int* __restrict__ cnt, unsigned long long* __restrict__ minbase,
                          unsigned long long* __restrict__ maxbase) {
    const int b = blockIdx.x, chunk = blockIdx.y;
    const int t = threadIdx.x, wave = t >> 6, lane = t & 63;
    const int w8 = wave * RPW;
    __shared__ float4 rows[R][F4];   // 32 KB
    __shared__ float4 red[4][F4];    // 4 KB

    const float4* rbase = reinterpret_cast<const float4*>(ref_flow)
                        + ((size_t)b * N + (size_t)chunk * R) * F4;
    #pragma unroll
    for (int i = 0; i < RPW; ++i)
        gload_lds16(rbase + (size_t)(w8 + i) * F4 + lane, &rows[w8 + i][0]);
    asm volatile("s_waitcnt vmcnt(0)" ::: "memory");
    __syncthreads();

    float4 acc = make_float4(0.f, 0.f, 0.f, 0.f);
    #pragma unroll
    for (int i = 0; i < RPW; ++i) {
        float4 v = rows[w8 + i][lane];   // conflict-free: lane*16B consecutive
        acc.x += v.x; acc.y += v.y; acc.z += v.z; acc.w += v.w;
    }
    red[wave][lane] = acc;
    __syncthreads();
    if (wave == 0) {
        float4 a0 = red[0][lane], a1 = red[1][lane], a2 = red[2][lane], a3 = red[3][lane];
        float4 s = make_float4(a0.x + a1.x + a2.x + a3.x, a0.y + a1.y + a2.y + a3.y,
                               a0.z + a1.z + a2.z + a3.z, a0.w + a1.w + a2.w + a3.w);
        reinterpret_cast<float4*>(partial)[((size_t)b * CH + chunk) * F4 + lane] = s;
    }
    // zero-init per-batch slots + both last-arriver counters (boundary-flushed)
    if (chunk == 0) {
        if (t < 3) minbase[(size_t)b * 16 + t] = 0ull;
        if (t < 2) maxbase[(size_t)b * 16 + t] = 0ull;
        if (t == 0) { cnt[b * 32] = 0; cnt[(B + b) * 32] = 0; }
    }
}

// ---------------- K2: stage ref rows (issue first) + S-reduce overlapped -> dot1 from LDS
//                      + top3 slots; last-arriver: decode, Tv -> ws, out rows 0-2 ----------------
__global__ void k2_dot1(const float* __restrict__ ref_rgb, const float* __restrict__ ref_flow,
                        const float* __restrict__ partial, float* __restrict__ Tvg,
                        float* __restrict__ out,
                        unsigned long long* __restrict__ minbase, int* __restrict__ cnt) {
    const int b = blockIdx.x, chunk = blockIdx.y;
    const int t = threadIdx.x, wave = t >> 6, lane = t & 63;
    const int w8 = wave * RPW;
    __shared__ float4 rows[R][F4];   // 32 KB
    __shared__ float  S[F];
    __shared__ float  scoreS[R];
    __shared__ int    chosen[3];
    __shared__ int    lastFlag;

    unsigned long long* minslot = minbase + (size_t)b * 16;

    // 1) issue the ref-row staging (drains under the S-reduce)
    const float4* rbase = reinterpret_cast<const float4*>(ref_flow)
                        + ((size_t)b * N + (size_t)chunk * R) * F4;
    #pragma unroll
    for (int i = 0; i < RPW; ++i)
        gload_lds16(rbase + (size_t)(w8 + i) * F4 + lane, &rows[w8 + i][0]);

    // 2) redundant S-reduce: same 128KB per batch for all 128 blocks -> L2 broadcast
    {
        float sacc = 0.f;
        const float* pb = partial + (size_t)b * CH * F + t;
        #pragma unroll 8
        for (int p = 0; p < CH; ++p) sacc += pb[(size_t)p * F];
        S[t] = sacc;
    }
    asm volatile("s_waitcnt vmcnt(0)" ::: "memory");
    __syncthreads();

    // 3) dot1 from LDS
    {
        float4 s4 = reinterpret_cast<const float4*>(S)[lane];
        #pragma unroll
        for (int i = 0; i < RPW; ++i) {
            float4 a = rows[w8 + i][lane];
            float d = a.x * s4.x + a.y * s4.y + a.z * s4.z + a.w * s4.w;
            #pragma unroll
            for (int off = 32; off; off >>= 1) d += __shfl_xor(d, off);
            if (lane == 0) scoreS[w8 + i] = d;
        }
    }
    __syncthreads();

    // 4) wave0: top-3 min -> lock-free bubbling slot insert (exact top-3, order-free)
    if (wave == 0) {
        const unsigned gidx = (unsigned)(chunk * R + lane);
        unsigned long long inv = 0;   // lanes >= R: worst sentinel
        if (lane < R)
            inv = ~((((unsigned long long)sortable_f32(scoreS[lane])) << 32) | (unsigned long long)gidx);
        unsigned long long cur = inv;
        for (int k = 0; k < 3; ++k) {
            unsigned long long m = cur;
            #pragma unroll
            for (int off = 32; off; off >>= 1) {
                unsigned long long o = __shfl_xor(m, off);
                if (o > m) m = o;
            }
            if (lane == 0) {
                unsigned long long x = m;
                #pragma unroll
                for (int s = 0; s < 3; ++s) {
                    unsigned long long old = atomicMax(&minslot[s], x);
                    x = (old < x) ? old : x;
                }
            }
            if (cur == m) cur = 0;
        }
    }

    // 5) last arriver per batch (no spin): decode top-3, Tv -> ws, out rows 0-2
    asm volatile("s_waitcnt vmcnt(0)" ::: "memory");   // my slot atomics globally visible
    __syncthreads();
    if (t == 0) {
        int old = __hip_atomic_fetch_add(cnt + b * 32, 1,
                                         __ATOMIC_RELAXED, __HIP_MEMORY_SCOPE_AGENT);
        lastFlag = (old == CH - 1);
    }
    __syncthreads();
    if (lastFlag) {
        if (t == 0) {
            unsigned long long y0 = agent_load_u64(&minslot[0]);
            unsigned long long y1 = agent_load_u64(&minslot[1]);
            unsigned long long y2 = agent_load_u64(&minslot[2]);
            unsigned long long tmp;
            if (y1 > y0) { tmp = y0; y0 = y1; y1 = tmp; }
            if (y2 > y0) { tmp = y0; y0 = y2; y2 = tmp; }
            if (y2 > y1) { tmp = y1; y1 = y2; y2 = tmp; }
            chosen[0] = (int)((~y0) & 0xFFFFFFFFull);
            chosen[1] = (int)((~y1) & 0xFFFFFFFFull);
            chosen[2] = (int)((~y2) & 0xFFFFFFFFull);
        }
        __syncthreads();
        const int i0 = chosen[0], i1 = chosen[1], i2 = chosen[2];
        Tvg[(size_t)b * F + t] = ref_flow[((size_t)b * N + i0) * F + t]
                               + ref_flow[((size_t)b * N + i1) * F + t]
                               + ref_flow[((size_t)b * N + i2) * F + t];
        out[((size_t)b * 5 + 0) * F + t] = ref_rgb[((size_t)b * N + i0) * F + t];
        out[((size_t)b * 5 + 1) * F + t] = ref_rgb[((size_t)b * N + i1) * F + t];
        out[((size_t)b * 5 + 2) * F + t] = ref_rgb[((size_t)b * N + i2) * F + t];
    }
}

// ---------------- K3: stage sup rows + Tv load -> dot2 from LDS + top2 slots;
//                      last-arriver: decode + gather rows 3-4 ----------------
__global__ void k3_dot2(const float* __restrict__ sup_rgb, const float* __restrict__ sup_flow,
                        const float* __restrict__ Tvg, float* __restrict__ out,
                        unsigned long long* __restrict__ maxbase, int* __restrict__ cnt) {
    const int b = blockIdx.x, chunk = blockIdx.y;
    const int t = threadIdx.x, wave = t >> 6, lane = t & 63;
    const int w8 = wave * RPW;
    __shared__ float4 rows[R][F4];   // 32 KB
    __shared__ float  scoreS[R];
    __shared__ int    chosen[2];
    __shared__ int    lastFlag;

    unsigned long long* maxslot = maxbase + (size_t)b * 16;

    // 1) issue the cold sup staging immediately; Tv load drains alongside
    const float4* sbase = reinterpret_cast<const float4*>(sup_flow)
                        + ((size_t)b * N + (size_t)chunk * R) * F4;
    #pragma unroll
    for (int i = 0; i < RPW; ++i)
        gload_lds16(sbase + (size_t)(w8 + i) * F4 + lane, &rows[w8 + i][0]);
    float4 tv4 = reinterpret_cast<const float4*>(Tvg)[(size_t)b * F4 + lane];

    asm volatile("s_waitcnt vmcnt(0)" ::: "memory");
    __syncthreads();

    // 2) dot2 from LDS
    #pragma unroll
    for (int i = 0; i < RPW; ++i) {
        float4 a = rows[w8 + i][lane];
        float d = a.x * tv4.x + a.y * tv4.y + a.z * tv4.z + a.w * tv4.w;
        #pragma unroll
        for (int off = 32; off; off >>= 1) d += __shfl_xor(d, off);
        if (lane == 0) scoreS[w8 + i] = d;
    }
    __syncthreads();

    // 3) wave0: top-2 max -> slot insert
    if (wave == 0) {
        const unsigned gidx = (unsigned)(chunk * R + lane);
        unsigned long long pk = 0;   // lanes >= R: worst sentinel
        if (lane < R)
            pk = (((unsigned long long)sortable_f32(scoreS[lane])) << 32) |
                 (unsigned long long)(0xFFFFFFFFu - gidx);
        unsigned long long cur = pk;
        for (int k = 0; k < 2; ++k) {
            unsigned long long m = cur;
            #pragma unroll
            for (int off = 32; off; off >>= 1) {
                unsigned long long o = __shfl_xor(m, off);
                if (o > m) m = o;
            }
            if (lane == 0) {
                unsigned long long x = m;
                #pragma unroll
                for (int s = 0; s < 2; ++s) {
                    unsigned long long old = atomicMax(&maxslot[s], x);
                    x = (old < x) ? old : x;
                }
            }
            if (cur == m) cur = 0;
        }
    }

    // 4) last arriver per batch (no spin) decodes top-2 and gathers rows 3-4
    asm volatile("s_waitcnt vmcnt(0)" ::: "memory");
    __syncthreads();
    if (t == 0) {
        int old = __hip_atomic_fetch_add(cnt + (B + b) * 32, 1,
                                         __ATOMIC_RELAXED, __HIP_MEMORY_SCOPE_AGENT);
        lastFlag = (old == CH - 1);
    }
    __syncthreads();
    if (lastFlag) {
        if (t == 0) {
            unsigned long long y0 = agent_load_u64(&maxslot[0]);
            unsigned long long y1 = agent_load_u64(&maxslot[1]);
            if (y1 > y0) { unsigned long long tmp = y0; y0 = y1; y1 = tmp; }
            chosen[0] = (int)(0xFFFFFFFFu - (unsigned)(y0 & 0xFFFFFFFFull));
            chosen[1] = (int)(0xFFFFFFFFu - (unsigned)(y1 & 0xFFFFFFFFull));
        }
        __syncthreads();
        out[((size_t)b * 5 + 3) * F + t] = sup_rgb[((size_t)b * N + chosen[0]) * F + t];
        out[((size_t)b * 5 + 4) * F + t] = sup_rgb[((size_t)b * N + chosen[1]) * F + t];
    }
}

extern "C" void kernel_launch(void* const* d_in, const int* in_sizes, int n_in,
                              void* d_out, int out_size, void* d_ws, size_t ws_size,
                              hipStream_t stream) {
    const float* ref_rgb  = (const float*)d_in[0];
    const float* ref_flow = (const float*)d_in[1];
    const float* sup_rgb  = (const float*)d_in[2];
    const float* sup_flow = (const float*)d_in[3];
    float* out = (float*)d_out;

    // ws: [0,2048) counters | [4096,5120) minslots | [8192,9216) maxslots |
    //     [12288,20480) Tv (8 x 256 f32) | [32768, +1MB) partial
    int* cnt = (int*)d_ws;
    unsigned long long* minbase = (unsigned long long*)((char*)d_ws + 4096);
    unsigned long long* maxbase = (unsigned long long*)((char*)d_ws + 8192);
    float* Tvg     = (float*)((char*)d_ws + 12288);
    float* partial = (float*)((char*)d_ws + 32768);

    k1_colsum<<<dim3(B, CH), 256, 0, stream>>>(ref_flow, partial, cnt, minbase, maxbase);
    k2_dot1<<<dim3(B, CH), 256, 0, stream>>>(ref_rgb, ref_flow, partial, Tvg, out, minbase, cnt);
    k3_dot2<<<dim3(B, CH), 256, 0, stream>>>(sup_rgb, sup_flow, Tvg, out, maxbase, cnt);
}

// Round 14
// 41.259 us; speedup vs baseline: 1.3170x; 1.2441x over previous
//
#include <hip/hip_runtime.h>

// (B,N,F) = (8, 4096, 256), fp32 in/out. out = (B, 5, F).
// Structure (proven best, r8 = 41.4 us): 3 kernels, no in-kernel inter-block waits,
// cross-block results via lock-free slot atomics + last-arriver gathers.
constexpr int B = 8;
constexpr int N = 4096;
constexpr int F = 256;
constexpr int F4 = F / 4;        // 64 float4 per row
constexpr int CH1 = 64;          // K1/K2 chunks per batch
constexpr int R1 = N / CH1;      // 64 rows per block
constexpr int W1 = R1 / 4;       // 16 rows per wave
constexpr int CH3 = 128;         // K3 chunks per batch
constexpr int R3 = N / CH3;      // 32 rows per block
constexpr int W3 = R3 / 4;       // 8 rows per wave

// Monotone float->uint mapping: f<g  <=>  sortable(f)<sortable(g)
__device__ __forceinline__ unsigned sortable_f32(float f) {
    unsigned u = __float_as_uint(f);
    return (u & 0x80000000u) ? ~u : (u | 0x80000000u);
}

__device__ __forceinline__ unsigned long long agent_load_u64(const unsigned long long* p) {
    return __hip_atomic_load(p, __ATOMIC_RELAXED, __HIP_MEMORY_SCOPE_AGENT);
}

// ---------------- K1: column partials of ref_flow + zero-init sync state ----------------
__global__ void k1_colsum(const float* __restrict__ ref_flow, float* __restrict__ partial,
                          int* __restrict__ cnt, unsigned long long* __restrict__ minbase,
                          unsigned long long* __restrict__ maxbase) {
    const int b = blockIdx.x, chunk = blockIdx.y;
    const int t = threadIdx.x, wave = t >> 6, lane = t & 63;
    const int w16 = wave * W1;
    __shared__ float4 red[4][F4];

    const float4* rbase = reinterpret_cast<const float4*>(ref_flow)
                        + ((size_t)b * N + (size_t)chunk * R1) * F4;
    float4 v[W1];
    #pragma unroll
    for (int i = 0; i < W1; ++i) v[i] = rbase[(size_t)(w16 + i) * F4 + lane];

    float4 acc = make_float4(0.f, 0.f, 0.f, 0.f);
    #pragma unroll
    for (int i = 0; i < W1; ++i) {
        acc.x += v[i].x; acc.y += v[i].y; acc.z += v[i].z; acc.w += v[i].w;
    }
    red[wave][lane] = acc;
    __syncthreads();
    if (wave == 0) {
        float4 a0 = red[0][lane], a1 = red[1][lane], a2 = red[2][lane], a3 = red[3][lane];
        float4 s = make_float4(a0.x + a1.x + a2.x + a3.x, a0.y + a1.y + a2.y + a3.y,
                               a0.z + a1.z + a2.z + a3.z, a0.w + a1.w + a2.w + a3.w);
        reinterpret_cast<float4*>(partial)[((size_t)b * CH1 + chunk) * F4 + lane] = s;
    }
    // zero-init per-batch slots/counters (visible to K2/K3 via kernel boundary)
    if (chunk == 0) {
        if (t < 3) minbase[(size_t)b * 16 + t] = 0ull;
        if (t < 2) maxbase[(size_t)b * 16 + t] = 0ull;
        if (t == 0) cnt[b * 32] = 0;
    }
}

// ---------------- K2: redundant S-reduce + ref dots (L2/L3) + wave top-3 min -> slots ----------------
__global__ void k2_dot1(const float* __restrict__ ref_flow, const float* __restrict__ partial,
                        unsigned long long* __restrict__ minbase) {
    const int b = blockIdx.x, chunk = blockIdx.y;
    const int t = threadIdx.x, wave = t >> 6, lane = t & 63;
    const int w16 = wave * W1;
    __shared__ float S[F];
    __shared__ float scoreS[R1];

    float sacc = 0.f;
    const float* pb = partial + (size_t)b * CH1 * F + t;
    #pragma unroll 8
    for (int p = 0; p < CH1; ++p) sacc += pb[(size_t)p * F];
    S[t] = sacc;
    __syncthreads();

    const float4* rbase = reinterpret_cast<const float4*>(ref_flow)
                        + ((size_t)b * N + (size_t)chunk * R1) * F4;
    float4 s4 = reinterpret_cast<const float4*>(S)[lane];
    float4 v[W1];
    #pragma unroll
    for (int i = 0; i < W1; ++i) v[i] = rbase[(size_t)(w16 + i) * F4 + lane];
    #pragma unroll
    for (int i = 0; i < W1; ++i) {
        float d = v[i].x * s4.x + v[i].y * s4.y + v[i].z * s4.z + v[i].w * s4.w;
        #pragma unroll
        for (int off = 32; off; off >>= 1) d += __shfl_xor(d, off);
        if (lane == 0) scoreS[w16 + i] = d;
    }
    __syncthreads();

    if (wave == 0) {
        unsigned long long* minslot = minbase + (size_t)b * 16;
        // inv = ~packed: larger inv == smaller (score, idx). R1 == 64 == lanes.
        const unsigned gidx = (unsigned)(chunk * R1 + lane);
        unsigned long long inv =
            ~((((unsigned long long)sortable_f32(scoreS[lane])) << 32) | (unsigned long long)gidx);
        unsigned long long cur = inv;
        for (int k = 0; k < 3; ++k) {
            unsigned long long m = cur;
            #pragma unroll
            for (int off = 32; off; off >>= 1) {
                unsigned long long o = __shfl_xor(m, off);
                if (o > m) m = o;
            }
            if (lane == 0) {
                unsigned long long x = m;   // lock-free bubbling insert: exact top-3
                #pragma unroll
                for (int s = 0; s < 3; ++s) {
                    unsigned long long old = atomicMax(&minslot[s], x);
                    x = (old < x) ? old : x;
                }
            }
            if (cur == m) cur = 0;
        }
    }
}

// ---------------- K3: decode top-3, Tv, rows 0-2, sup dots, top-2 max, last-arriver gather ----------------
__global__ void k3_dot2(const float* __restrict__ ref_rgb, const float* __restrict__ ref_flow,
                        const float* __restrict__ sup_rgb, const float* __restrict__ sup_flow,
                        float* __restrict__ out, const unsigned long long* __restrict__ minbase,
                        unsigned long long* __restrict__ maxbase, int* __restrict__ cnt) {
    const int b = blockIdx.x, chunk = blockIdx.y;
    const int t = threadIdx.x, wave = t >> 6, lane = t & 63;
    const int w8 = wave * W3;
    __shared__ float Tv[F];
    __shared__ float scoreS[R3];
    __shared__ int chosen[3];
    __shared__ int lastFlag;

    // issue the sup_flow loads first (L3-hot in timed replays; overlaps decode/Tv build)
    const float4* sbase = reinterpret_cast<const float4*>(sup_flow)
                        + ((size_t)b * N + (size_t)chunk * R3) * F4;
    float4 v[W3];
    #pragma unroll
    for (int i = 0; i < W3; ++i) v[i] = sbase[(size_t)(w8 + i) * F4 + lane];

    // decode top-3 (plain loads: K2 finished at kernel boundary)
    if (t == 0) {
        unsigned long long y0 = minbase[(size_t)b * 16 + 0];
        unsigned long long y1 = minbase[(size_t)b * 16 + 1];
        unsigned long long y2 = minbase[(size_t)b * 16 + 2];
        unsigned long long tmp;
        if (y1 > y0) { tmp = y0; y0 = y1; y1 = tmp; }
        if (y2 > y0) { tmp = y0; y0 = y2; y2 = tmp; }
        if (y2 > y1) { tmp = y1; y1 = y2; y2 = tmp; }
        chosen[0] = (int)((~y0) & 0xFFFFFFFFull);
        chosen[1] = (int)((~y1) & 0xFFFFFFFFull);
        chosen[2] = (int)((~y2) & 0xFFFFFFFFull);
    }
    __syncthreads();
    {
        const int i0 = chosen[0], i1 = chosen[1], i2 = chosen[2];
        Tv[t] = ref_flow[((size_t)b * N + i0) * F + t]      // L3-resident
              + ref_flow[((size_t)b * N + i1) * F + t]
              + ref_flow[((size_t)b * N + i2) * F + t];
        if (chunk == 0) {
            out[((size_t)b * 5 + 0) * F + t] = ref_rgb[((size_t)b * N + i0) * F + t];
            out[((size_t)b * 5 + 1) * F + t] = ref_rgb[((size_t)b * N + i1) * F + t];
            out[((size_t)b * 5 + 2) * F + t] = ref_rgb[((size_t)b * N + i2) * F + t];
        }
    }
    __syncthreads();

    float4 tv4 = reinterpret_cast<const float4*>(Tv)[lane];
    #pragma unroll
    for (int i = 0; i < W3; ++i) {
        float d = v[i].x * tv4.x + v[i].y * tv4.y + v[i].z * tv4.z + v[i].w * tv4.w;
        #pragma unroll
        for (int off = 32; off; off >>= 1) d += __shfl_xor(d, off);
        if (lane == 0) scoreS[w8 + i] = d;
    }
    __syncthreads();

    if (wave == 0) {
        unsigned long long* maxslot = maxbase + (size_t)b * 16;
        // packed: larger == larger score, tie -> smaller index. lanes >= R3: worst sentinel 0.
        const unsigned gidx = (unsigned)(chunk * R3 + lane);
        unsigned long long pk = 0;
        if (lane < R3)
            pk = (((unsigned long long)sortable_f32(scoreS[lane])) << 32) |
                 (unsigned long long)(0xFFFFFFFFu - gidx);
        unsigned long long cur = pk;
        for (int k = 0; k < 2; ++k) {
            unsigned long long m = cur;
            #pragma unroll
            for (int off = 32; off; off >>= 1) {
                unsigned long long o = __shfl_xor(m, off);
                if (o > m) m = o;
            }
            if (lane == 0) {
                unsigned long long x = m;
                #pragma unroll
                for (int s = 0; s < 2; ++s) {
                    unsigned long long old = atomicMax(&maxslot[s], x);
                    x = (old < x) ? old : x;
                }
            }
            if (cur == m) cur = 0;
        }
    }

    // last arriver per batch gathers rows 3-4 (no spin; vmcnt(0) acks my atomics first)
    asm volatile("s_waitcnt vmcnt(0)" ::: "memory");
    __syncthreads();
    if (t == 0) {
        int old = __hip_atomic_fetch_add(cnt + b * 32, 1, __ATOMIC_RELAXED, __HIP_MEMORY_SCOPE_AGENT);
        lastFlag = (old == CH3 - 1);
    }
    __syncthreads();
    if (lastFlag) {
        if (t == 0) {
            unsigned long long y0 = agent_load_u64(maxbase + (size_t)b * 16 + 0);
            unsigned long long y1 = agent_load_u64(maxbase + (size_t)b * 16 + 1);
            if (y1 > y0) { unsigned long long tmp = y0; y0 = y1; y1 = tmp; }
            chosen[0] = (int)(0xFFFFFFFFu - (unsigned)(y0 & 0xFFFFFFFFull));
            chosen[1] = (int)(0xFFFFFFFFu - (unsigned)(y1 & 0xFFFFFFFFull));
        }
        __syncthreads();
        out[((size_t)b * 5 + 3) * F + t] = sup_rgb[((size_t)b * N + chosen[0]) * F + t];
        out[((size_t)b * 5 + 4) * F + t] = sup_rgb[((size_t)b * N + chosen[1]) * F + t];
    }
}

extern "C" void kernel_launch(void* const* d_in, const int* in_sizes, int n_in,
                              void* d_out, int out_size, void* d_ws, size_t ws_size,
                              hipStream_t stream) {
    const float* ref_rgb  = (const float*)d_in[0];
    const float* ref_flow = (const float*)d_in[1];
    const float* sup_rgb  = (const float*)d_in[2];
    const float* sup_flow = (const float*)d_in[3];
    float* out = (float*)d_out;

    // ws: [0,1024) counters (8 batches x 128B) | [4096,5120) minslots |
    //     [8192,9216) maxslots | [16384, +512KB) partial
    int* cnt = (int*)d_ws;
    unsigned long long* minbase = (unsigned long long*)((char*)d_ws + 4096);
    unsigned long long* maxbase = (unsigned long long*)((char*)d_ws + 8192);
    float* partial = (float*)((char*)d_ws + 16384);

    k1_colsum<<<dim3(B, CH1), 256, 0, stream>>>(ref_flow, partial, cnt, minbase, maxbase);
    k2_dot1<<<dim3(B, CH1), 256, 0, stream>>>(ref_flow, partial, minbase);
    k3_dot2<<<dim3(B, CH3), 256, 0, stream>>>(ref_rgb, ref_flow, sup_rgb, sup_flow,
                                              out, minbase, maxbase, cnt);
}